// Round 7
// baseline (428.745 us; speedup 1.0000x reference)
//
#include <hip/hip_runtime.h>

// Problem constants: B=16, NEG=128, S=128, D=512, N_PRED=12
#define DIM 512
#define M_ROWS 2048      // B*S

typedef __attribute__((ext_vector_type(8))) short short8;   // 8 bf16 (4 VGPRs)
typedef __attribute__((ext_vector_type(4))) float f32x4;

// f32 -> bf16 round-to-nearest-even (inputs are well-scaled, no NaN expected)
static __device__ __forceinline__ short f2bf(float x) {
    unsigned int u = __builtin_bit_cast(unsigned int, x);
    u += 0x7fffu + ((u >> 16) & 1u);
    return (short)(u >> 16);
}

// ---------------- Kernel 1: c_proj = c @ W[k]^T + b[k], bf16 MFMA ----------------
// (unchanged from R3 — ~4 us, verified)
#define K1_PAD 40
__global__ __launch_bounds__(256) void cproj_mfma(
    const float* __restrict__ c, const float* __restrict__ W,
    const float* __restrict__ bias, const int* __restrict__ kptr,
    float* __restrict__ cp) {
    const int ksel = kptr[0];
    const float* __restrict__ Wk = W + (size_t)ksel * DIM * DIM;
    const float* __restrict__ bk = bias + (size_t)ksel * DIM;

    __shared__ short Alds[64][K1_PAD];
    __shared__ short Blds[64][K1_PAD];

    const int bm = blockIdx.x & 31;
    const int bn = blockIdx.x >> 5;
    const int t  = threadIdx.x;
    const int lane = t & 63;
    const int wv   = t >> 6;

    const int srow = t >> 2;
    const int sk   = (t & 3) * 8;

    const float* Ap = c  + (size_t)(bm * 64 + srow) * DIM + sk;
    const float* Bp = Wk + (size_t)(bn * 64 + srow) * DIM + sk;

    float4 a0 = *(const float4*)Ap,       a1 = *(const float4*)(Ap + 4);
    float4 b0 = *(const float4*)Bp,       b1 = *(const float4*)(Bp + 4);

    f32x4 acc[4] = {};

    const int frow = lane & 15;
    const int fk   = (lane >> 4) * 8;

    for (int step = 0; step < 16; ++step) {
        __syncthreads();
        short8 av, bv;
        av[0] = f2bf(a0.x); av[1] = f2bf(a0.y); av[2] = f2bf(a0.z); av[3] = f2bf(a0.w);
        av[4] = f2bf(a1.x); av[5] = f2bf(a1.y); av[6] = f2bf(a1.z); av[7] = f2bf(a1.w);
        bv[0] = f2bf(b0.x); bv[1] = f2bf(b0.y); bv[2] = f2bf(b0.z); bv[3] = f2bf(b0.w);
        bv[4] = f2bf(b1.x); bv[5] = f2bf(b1.y); bv[6] = f2bf(b1.z); bv[7] = f2bf(b1.w);
        *(short8*)&Alds[srow][sk] = av;
        *(short8*)&Blds[srow][sk] = bv;
        __syncthreads();
        if (step < 15) {
            const int off = (step + 1) * 32;
            a0 = *(const float4*)(Ap + off); a1 = *(const float4*)(Ap + off + 4);
            b0 = *(const float4*)(Bp + off); b1 = *(const float4*)(Bp + off + 4);
        }
        const short8 bfrag = *(const short8*)&Blds[wv * 16 + frow][fk];
#pragma unroll
        for (int f = 0; f < 4; ++f) {
            const short8 afrag = *(const short8*)&Alds[f * 16 + frow][fk];
            acc[f] = __builtin_amdgcn_mfma_f32_16x16x32_bf16(afrag, bfrag, acc[f], 0, 0, 0);
        }
    }

    const int col = bn * 64 + wv * 16 + frow;
    const float bias_v = bk[col];
    const int r0 = (lane >> 4) * 4;
#pragma unroll
    for (int f = 0; f < 4; ++f)
#pragma unroll
        for (int r = 0; r < 4; ++r)
            cp[(size_t)(bm * 64 + f * 16 + r0 + r) * DIM + col] = acc[f][r] + bias_v;
}

// ---------------- Kernel 2: out[b,n,s] = (1/512) * dot(cp[b,s,:], z[b,n,s,:]) ----
// DIAGNOSTIC BUILD: identical structure to R5 (4-deep register pipeline), but
// the whole body repeats `reps` times (host passes reps=4, rep_delta=0).
// Each rep recomputes and rewrites the SAME outputs (idempotent, deterministic);
// rep_delta is a runtime 0 so the compiler cannot CSE loads across reps.
// Purpose: push this dispatch to ~460 us so it finally lands in the top-5
// counter table and we can read hbm_gbps / VALUBusy / Occupancy / FETCH_SIZE.
#define NSTR ((size_t)4 * 128 * 512)   // 4 negatives ahead in z (floats)
#define LD4(p) (*(const float4*)(p))

__global__ __launch_bounds__(256, 6) void dot_kernel(
    const float* __restrict__ z, const float* __restrict__ cp,
    float* __restrict__ out, int reps, size_t rep_delta) {
    const int bs   = blockIdx.x;             // b*128 + s (0..2047)
    const int wave = threadIdx.x >> 6;       // 0..3
    const int lane = threadIdx.x & 63;
    const int b = bs >> 7;
    const int s = bs & 127;

    // cp row -> registers (all 4 waves broadcast-read the same 2 KB via L1)
    const float* cpr = cp + (size_t)bs * DIM + lane * 8;
    const float4 c0 = LD4(cpr);
    const float4 c1 = LD4(cpr + 4);

    const float* zbase = z + (((size_t)(b * 128 + wave)) * 128 + s) * DIM + lane * 8;
    float* outp = out + ((size_t)b * 128 + wave) * 128 + s;

    for (int rep = 0; rep < reps; ++rep) {
        const float* zp = zbase;

        // prologue: fill 4 pipeline slots (8 loads in flight)
        float4 zA0 = LD4(zp + 0 * NSTR), zA1 = LD4(zp + 0 * NSTR + 4);
        float4 zB0 = LD4(zp + 1 * NSTR), zB1 = LD4(zp + 1 * NSTR + 4);
        float4 zC0 = LD4(zp + 2 * NSTR), zC1 = LD4(zp + 2 * NSTR + 4);
        float4 zD0 = LD4(zp + 3 * NSTR), zD1 = LD4(zp + 3 * NSTR + 4);

#define SLOT(Z0, Z1, II)                                                      \
    {                                                                          \
        float acc = Z0.x * c0.x;                                               \
        acc = fmaf(Z0.y, c0.y, acc);                                           \
        acc = fmaf(Z0.z, c0.z, acc);                                           \
        acc = fmaf(Z0.w, c0.w, acc);                                           \
        acc = fmaf(Z1.x, c1.x, acc);                                           \
        acc = fmaf(Z1.y, c1.y, acc);                                           \
        acc = fmaf(Z1.z, c1.z, acc);                                           \
        acc = fmaf(Z1.w, c1.w, acc);                                           \
        if ((II) + 4 < 32) {  /* reload this slot 4 n-steps ahead */           \
            Z0 = LD4(zp + (size_t)((II) + 4) * NSTR);                          \
            Z1 = LD4(zp + (size_t)((II) + 4) * NSTR + 4);                      \
        }                                                                      \
        _Pragma("unroll")                                                      \
        for (int off = 32; off; off >>= 1) acc += __shfl_xor(acc, off);        \
        if (lane == 0) outp[(size_t)(II) * 4 * 128] = acc * (1.0f / 512.0f);   \
    }

#pragma unroll
        for (int g = 0; g < 8; ++g) {
            SLOT(zA0, zA1, g * 4 + 0)
            SLOT(zB0, zB1, g * 4 + 1)
            SLOT(zC0, zC1, g * 4 + 2)
            SLOT(zD0, zD1, g * 4 + 3)
        }
#undef SLOT
        zbase += rep_delta;   // runtime 0: defeats cross-rep CSE, keeps semantics
    }
}

extern "C" void kernel_launch(void* const* d_in, const int* in_sizes, int n_in,
                              void* d_out, int out_size, void* d_ws, size_t ws_size,
                              hipStream_t stream) {
    const float* c    = (const float*)d_in[0];
    const float* z    = (const float*)d_in[1];
    const float* W    = (const float*)d_in[2];
    const float* bias = (const float*)d_in[3];
    const int*   kptr = (const int*)d_in[4];
    float* out = (float*)d_out;
    float* cp  = (float*)d_ws;   // 2048*512*4 = 4 MB scratch for c_proj

    // Kernel 1: 32 M-tiles x 8 N-tiles = 256 blocks, bf16 MFMA
    cproj_mfma<<<dim3(256), dim3(256), 0, stream>>>(c, W, bias, kptr, cp);
    // Kernel 2: DIAGNOSTIC reps=4 (idempotent) to surface counters for K2
    dot_kernel<<<dim3(2048), dim3(256), 0, stream>>>(z, cp, out, 4, (size_t)0);
}

// Round 8
// 118.959 us; speedup vs baseline: 3.6041x; 3.6041x over previous
//
#include <hip/hip_runtime.h>

// Problem constants: B=16, NEG=128, S=128, D=512, N_PRED=12
#define DIM 512
#define M_ROWS 2048      // B*S

typedef __attribute__((ext_vector_type(8))) short short8;   // 8 bf16 (4 VGPRs)
typedef __attribute__((ext_vector_type(4))) float f32x4;

// f32 -> bf16 round-to-nearest-even (inputs are well-scaled, no NaN expected)
static __device__ __forceinline__ short f2bf(float x) {
    unsigned int u = __builtin_bit_cast(unsigned int, x);
    u += 0x7fffu + ((u >> 16) & 1u);
    return (short)(u >> 16);
}

// ---------------- Kernel 1: c_proj = c @ W[k]^T + b[k], bf16 MFMA ----------------
// (unchanged from R3 — ~5 us, verified)
#define K1_PAD 40
__global__ __launch_bounds__(256) void cproj_mfma(
    const float* __restrict__ c, const float* __restrict__ W,
    const float* __restrict__ bias, const int* __restrict__ kptr,
    float* __restrict__ cp) {
    const int ksel = kptr[0];
    const float* __restrict__ Wk = W + (size_t)ksel * DIM * DIM;
    const float* __restrict__ bk = bias + (size_t)ksel * DIM;

    __shared__ short Alds[64][K1_PAD];
    __shared__ short Blds[64][K1_PAD];

    const int bm = blockIdx.x & 31;
    const int bn = blockIdx.x >> 5;
    const int t  = threadIdx.x;
    const int lane = t & 63;
    const int wv   = t >> 6;

    const int srow = t >> 2;
    const int sk   = (t & 3) * 8;

    const float* Ap = c  + (size_t)(bm * 64 + srow) * DIM + sk;
    const float* Bp = Wk + (size_t)(bn * 64 + srow) * DIM + sk;

    float4 a0 = *(const float4*)Ap,       a1 = *(const float4*)(Ap + 4);
    float4 b0 = *(const float4*)Bp,       b1 = *(const float4*)(Bp + 4);

    f32x4 acc[4] = {};

    const int frow = lane & 15;
    const int fk   = (lane >> 4) * 8;

    for (int step = 0; step < 16; ++step) {
        __syncthreads();
        short8 av, bv;
        av[0] = f2bf(a0.x); av[1] = f2bf(a0.y); av[2] = f2bf(a0.z); av[3] = f2bf(a0.w);
        av[4] = f2bf(a1.x); av[5] = f2bf(a1.y); av[6] = f2bf(a1.z); av[7] = f2bf(a1.w);
        bv[0] = f2bf(b0.x); bv[1] = f2bf(b0.y); bv[2] = f2bf(b0.z); bv[3] = f2bf(b0.w);
        bv[4] = f2bf(b1.x); bv[5] = f2bf(b1.y); bv[6] = f2bf(b1.z); bv[7] = f2bf(b1.w);
        *(short8*)&Alds[srow][sk] = av;
        *(short8*)&Blds[srow][sk] = bv;
        __syncthreads();
        if (step < 15) {
            const int off = (step + 1) * 32;
            a0 = *(const float4*)(Ap + off); a1 = *(const float4*)(Ap + off + 4);
            b0 = *(const float4*)(Bp + off); b1 = *(const float4*)(Bp + off + 4);
        }
        const short8 bfrag = *(const short8*)&Blds[wv * 16 + frow][fk];
#pragma unroll
        for (int f = 0; f < 4; ++f) {
            const short8 afrag = *(const short8*)&Alds[f * 16 + frow][fk];
            acc[f] = __builtin_amdgcn_mfma_f32_16x16x32_bf16(afrag, bfrag, acc[f], 0, 0, 0);
        }
    }

    const int col = bn * 64 + wv * 16 + frow;
    const float bias_v = bk[col];
    const int r0 = (lane >> 4) * 4;
#pragma unroll
    for (int f = 0; f < 4; ++f)
#pragma unroll
        for (int r = 0; r < 4; ++r)
            cp[(size_t)(bm * 64 + f * 16 + r0 + r) * DIM + col] = acc[f][r] + bias_v;
}

// ---------------- Kernel 2: out[b,n,s] = (1/512) * dot(cp[b,s,:], z[b,n,s,:]) ----
// R5 structure (block per (b,s) row, cp in registers, 4-deep pipeline) with ONE
// change: canonical coalescing. Each 2 KB row is split into two CONTIGUOUS 1 KB
// halves — lane i loads float4 at row[4i] (floats 0..255) and row[256+4i]
// (floats 256..511). One load instruction = one fully-used contiguous 1 KB
// (16 segments), vs the old lane*8 interleave spanning 2 KB (32 half-used
// segments). Dot product is order-agnostic so the reduce is unchanged.
#define NSTR ((size_t)4 * 128 * 512)   // 4 negatives ahead in z (floats)
#define HALF 256                       // floats per contiguous half-row
#define LD4(p) (*(const float4*)(p))

__global__ __launch_bounds__(256, 6) void dot_kernel(
    const float* __restrict__ z, const float* __restrict__ cp,
    float* __restrict__ out) {
    const int bs   = blockIdx.x;             // b*128 + s (0..2047)
    const int wave = threadIdx.x >> 6;       // 0..3
    const int lane = threadIdx.x & 63;
    const int b = bs >> 7;
    const int s = bs & 127;

    // cp row -> registers: contiguous halves (lane*4 within each 1 KB half)
    const float* cpr = cp + (size_t)bs * DIM + lane * 4;
    const float4 c0 = LD4(cpr);
    const float4 c1 = LD4(cpr + HALF);

    // wave handles n = wave + 4*i, i = 0..31
    const float* zp = z + (((size_t)(b * 128 + wave)) * 128 + s) * DIM + lane * 4;
    float* outp = out + ((size_t)b * 128 + wave) * 128 + s;

    // prologue: fill 4 pipeline slots (8 loads in flight)
    float4 zA0 = LD4(zp + 0 * NSTR), zA1 = LD4(zp + 0 * NSTR + HALF);
    float4 zB0 = LD4(zp + 1 * NSTR), zB1 = LD4(zp + 1 * NSTR + HALF);
    float4 zC0 = LD4(zp + 2 * NSTR), zC1 = LD4(zp + 2 * NSTR + HALF);
    float4 zD0 = LD4(zp + 3 * NSTR), zD1 = LD4(zp + 3 * NSTR + HALF);

#define SLOT(Z0, Z1, II)                                                      \
    {                                                                          \
        float acc = Z0.x * c0.x;                                               \
        acc = fmaf(Z0.y, c0.y, acc);                                           \
        acc = fmaf(Z0.z, c0.z, acc);                                           \
        acc = fmaf(Z0.w, c0.w, acc);                                           \
        acc = fmaf(Z1.x, c1.x, acc);                                           \
        acc = fmaf(Z1.y, c1.y, acc);                                           \
        acc = fmaf(Z1.z, c1.z, acc);                                           \
        acc = fmaf(Z1.w, c1.w, acc);                                           \
        if ((II) + 4 < 32) {  /* reload this slot 4 n-steps ahead */           \
            Z0 = LD4(zp + (size_t)((II) + 4) * NSTR);                          \
            Z1 = LD4(zp + (size_t)((II) + 4) * NSTR + HALF);                   \
        }                                                                      \
        _Pragma("unroll")                                                      \
        for (int off = 32; off; off >>= 1) acc += __shfl_xor(acc, off);        \
        if (lane == 0) outp[(size_t)(II) * 4 * 128] = acc * (1.0f / 512.0f);   \
    }

#pragma unroll
    for (int g = 0; g < 8; ++g) {
        SLOT(zA0, zA1, g * 4 + 0)
        SLOT(zB0, zB1, g * 4 + 1)
        SLOT(zC0, zC1, g * 4 + 2)
        SLOT(zD0, zD1, g * 4 + 3)
    }
#undef SLOT
}

extern "C" void kernel_launch(void* const* d_in, const int* in_sizes, int n_in,
                              void* d_out, int out_size, void* d_ws, size_t ws_size,
                              hipStream_t stream) {
    const float* c    = (const float*)d_in[0];
    const float* z    = (const float*)d_in[1];
    const float* W    = (const float*)d_in[2];
    const float* bias = (const float*)d_in[3];
    const int*   kptr = (const int*)d_in[4];
    float* out = (float*)d_out;
    float* cp  = (float*)d_ws;   // 2048*512*4 = 4 MB scratch for c_proj

    // Kernel 1: 32 M-tiles x 8 N-tiles = 256 blocks, bf16 MFMA
    cproj_mfma<<<dim3(256), dim3(256), 0, stream>>>(c, W, bias, kptr, cp);
    // Kernel 2: one block per (b,s) row = 2048 blocks, 4 waves, 4-deep pipeline
    dot_kernel<<<dim3(2048), dim3(256), 0, stream>>>(z, cp, out);
}

// Round 9
// 116.251 us; speedup vs baseline: 3.6881x; 1.0233x over previous
//
#include <hip/hip_runtime.h>

// Problem constants: B=16, NEG=128, S=128, D=512, N_PRED=12
#define DIM 512
#define M_ROWS 2048      // B*S

typedef __attribute__((ext_vector_type(8))) short short8;   // 8 bf16 (4 VGPRs)
typedef __attribute__((ext_vector_type(4))) float f32x4;

// f32 -> bf16 round-to-nearest-even (inputs are well-scaled, no NaN expected)
static __device__ __forceinline__ short f2bf(float x) {
    unsigned int u = __builtin_bit_cast(unsigned int, x);
    u += 0x7fffu + ((u >> 16) & 1u);
    return (short)(u >> 16);
}

// ---------------- Kernel 1: c_proj = c @ W[k]^T + b[k], bf16 MFMA ----------------
// (unchanged from R3 — ~5 us, verified)
#define K1_PAD 40
__global__ __launch_bounds__(256) void cproj_mfma(
    const float* __restrict__ c, const float* __restrict__ W,
    const float* __restrict__ bias, const int* __restrict__ kptr,
    float* __restrict__ cp) {
    const int ksel = kptr[0];
    const float* __restrict__ Wk = W + (size_t)ksel * DIM * DIM;
    const float* __restrict__ bk = bias + (size_t)ksel * DIM;

    __shared__ short Alds[64][K1_PAD];
    __shared__ short Blds[64][K1_PAD];

    const int bm = blockIdx.x & 31;
    const int bn = blockIdx.x >> 5;
    const int t  = threadIdx.x;
    const int lane = t & 63;
    const int wv   = t >> 6;

    const int srow = t >> 2;
    const int sk   = (t & 3) * 8;

    const float* Ap = c  + (size_t)(bm * 64 + srow) * DIM + sk;
    const float* Bp = Wk + (size_t)(bn * 64 + srow) * DIM + sk;

    float4 a0 = *(const float4*)Ap,       a1 = *(const float4*)(Ap + 4);
    float4 b0 = *(const float4*)Bp,       b1 = *(const float4*)(Bp + 4);

    f32x4 acc[4] = {};

    const int frow = lane & 15;
    const int fk   = (lane >> 4) * 8;

    for (int step = 0; step < 16; ++step) {
        __syncthreads();
        short8 av, bv;
        av[0] = f2bf(a0.x); av[1] = f2bf(a0.y); av[2] = f2bf(a0.z); av[3] = f2bf(a0.w);
        av[4] = f2bf(a1.x); av[5] = f2bf(a1.y); av[6] = f2bf(a1.z); av[7] = f2bf(a1.w);
        bv[0] = f2bf(b0.x); bv[1] = f2bf(b0.y); bv[2] = f2bf(b0.z); bv[3] = f2bf(b0.w);
        bv[4] = f2bf(b1.x); bv[5] = f2bf(b1.y); bv[6] = f2bf(b1.z); bv[7] = f2bf(b1.w);
        *(short8*)&Alds[srow][sk] = av;
        *(short8*)&Blds[srow][sk] = bv;
        __syncthreads();
        if (step < 15) {
            const int off = (step + 1) * 32;
            a0 = *(const float4*)(Ap + off); a1 = *(const float4*)(Ap + off + 4);
            b0 = *(const float4*)(Bp + off); b1 = *(const float4*)(Bp + off + 4);
        }
        const short8 bfrag = *(const short8*)&Blds[wv * 16 + frow][fk];
#pragma unroll
        for (int f = 0; f < 4; ++f) {
            const short8 afrag = *(const short8*)&Alds[f * 16 + frow][fk];
            acc[f] = __builtin_amdgcn_mfma_f32_16x16x32_bf16(afrag, bfrag, acc[f], 0, 0, 0);
        }
    }

    const int col = bn * 64 + wv * 16 + frow;
    const float bias_v = bk[col];
    const int r0 = (lane >> 4) * 4;
#pragma unroll
    for (int f = 0; f < 4; ++f)
#pragma unroll
        for (int r = 0; r < 4; ++r)
            cp[(size_t)(bm * 64 + f * 16 + r0 + r) * DIM + col] = acc[f][r] + bias_v;
}

// ---------------- Kernel 2: out[b,n,s] = (1/512) * dot(cp[b,s,:], z[b,n,s,:]) ----
// DMA-staged variant: z flows global -> LDS via global_load_lds (width 16),
// bypassing the VGPR-return path whose per-CU miss concurrency appears to cap
// delivered read BW at ~17 GB/s/CU (R6 diagnostic: 4.5 TB/s aggregate,
// source-tier-independent, depth-insensitive).
// Per wave: double-buffered groups of 4 negatives (8 KB each). Stage group
// g+1 (8 x global_load_lds), counted wait vmcnt(8) -> group g ready, process
// 4 slots from LDS (2 x ds_read_b128 + 8 FMA + 64-lane reduce each).
// LDS 4 waves x 2 bufs x 4 slots x 2 KB = 64 KB -> 2 blocks/CU, 8 waves/CU.
#define NSTR ((size_t)4 * 128 * 512)   // n += 4 stride in z (floats)

typedef const __attribute__((address_space(1))) void* gas_ptr;
typedef __attribute__((address_space(3))) void* las_ptr;

static __device__ __forceinline__ void stage1k(const float* g, float* l) {
    // each lane contributes 16 B; wave writes a contiguous 1 KB LDS line
    __builtin_amdgcn_global_load_lds((gas_ptr)(const void*)g, (las_ptr)(void*)l,
                                     16, 0, 0);
}

__global__ __launch_bounds__(256) void dot_kernel_lds(
    const float* __restrict__ z, const float* __restrict__ cp,
    float* __restrict__ out) {
    __shared__ float buf[4][2][4][512];      // [wave][dbuf][slot][floats] = 64 KB

    const int bs   = blockIdx.x;             // b*128 + s (0..2047)
    const int wave = threadIdx.x >> 6;       // 0..3
    const int lane = threadIdx.x & 63;
    const int b = bs >> 7;
    const int s = bs & 127;

    // cp row -> registers, contiguous 1 KB halves (loaded once, L1-broadcast)
    const float* cpr = cp + (size_t)bs * DIM + lane * 4;
    const float4 c0 = *(const float4*)cpr;
    const float4 c1 = *(const float4*)(cpr + 256);

    // wave handles n = wave + 4*i, i = 0..31; groups of 4 i's
    const float* zp = z + (((size_t)(b * 128 + wave)) * 128 + s) * DIM + lane * 4;
    float* outp = out + ((size_t)b * 128 + wave) * 128 + s;

#define STAGE_GROUP(GG, BSEL)                                                  \
    {                                                                          \
        _Pragma("unroll")                                                      \
        for (int sl = 0; sl < 4; ++sl) {                                       \
            const float* gsrc = zp + (size_t)((GG) * 4 + sl) * NSTR;           \
            stage1k(gsrc,       &buf[wave][BSEL][sl][0]);                      \
            stage1k(gsrc + 256, &buf[wave][BSEL][sl][256]);                    \
        }                                                                      \
    }

    STAGE_GROUP(0, 0)                        // prologue: group 0 in flight

    for (int g = 0; g < 8; ++g) {
        if (g < 7) {
            STAGE_GROUP(g + 1, (g + 1) & 1)  // keep next group in flight
            asm volatile("s_waitcnt vmcnt(8)" ::: "memory");   // group g ready
        } else {
            asm volatile("s_waitcnt vmcnt(0)" ::: "memory");   // drain last
        }
        __builtin_amdgcn_sched_barrier(0);
        const int bsel = g & 1;
#pragma unroll
        for (int sl = 0; sl < 4; ++sl) {
            const float4 z0 = *(const float4*)&buf[wave][bsel][sl][lane * 4];
            const float4 z1 = *(const float4*)&buf[wave][bsel][sl][256 + lane * 4];
            float acc = z0.x * c0.x;
            acc = fmaf(z0.y, c0.y, acc);
            acc = fmaf(z0.z, c0.z, acc);
            acc = fmaf(z0.w, c0.w, acc);
            acc = fmaf(z1.x, c1.x, acc);
            acc = fmaf(z1.y, c1.y, acc);
            acc = fmaf(z1.z, c1.z, acc);
            acc = fmaf(z1.w, c1.w, acc);
#pragma unroll
            for (int off = 32; off; off >>= 1) acc += __shfl_xor(acc, off);
            if (lane == 0)
                outp[(size_t)(g * 4 + sl) * 4 * 128] = acc * (1.0f / 512.0f);
        }
    }
#undef STAGE_GROUP
}

extern "C" void kernel_launch(void* const* d_in, const int* in_sizes, int n_in,
                              void* d_out, int out_size, void* d_ws, size_t ws_size,
                              hipStream_t stream) {
    const float* c    = (const float*)d_in[0];
    const float* z    = (const float*)d_in[1];
    const float* W    = (const float*)d_in[2];
    const float* bias = (const float*)d_in[3];
    const int*   kptr = (const int*)d_in[4];
    float* out = (float*)d_out;
    float* cp  = (float*)d_ws;   // 2048*512*4 = 4 MB scratch for c_proj

    // Kernel 1: 32 M-tiles x 8 N-tiles = 256 blocks, bf16 MFMA
    cproj_mfma<<<dim3(256), dim3(256), 0, stream>>>(c, W, bias, kptr, cp);
    // Kernel 2: one block per (b,s) row, DMA-staged z through LDS
    dot_kernel_lds<<<dim3(2048), dim3(256), 0, stream>>>(z, cp, out);
}

// Round 10
// 107.484 us; speedup vs baseline: 3.9889x; 1.0816x over previous
//
#include <hip/hip_runtime.h>

// Problem constants: B=16, NEG=128, S=128, D=512, N_PRED=12
#define DIM 512
#define M_ROWS 2048      // B*S

typedef __attribute__((ext_vector_type(8))) short short8;   // 8 bf16 (4 VGPRs)
typedef __attribute__((ext_vector_type(4))) float f32x4;

// f32 -> bf16 round-to-nearest-even (inputs are well-scaled, no NaN expected)
static __device__ __forceinline__ short f2bf(float x) {
    unsigned int u = __builtin_bit_cast(unsigned int, x);
    u += 0x7fffu + ((u >> 16) & 1u);
    return (short)(u >> 16);
}

// ---------------- Kernel 1: c_proj = c @ W[k]^T + b[k], bf16 MFMA ----------------
// (unchanged from R3 — ~5 us, verified)
#define K1_PAD 40
__global__ __launch_bounds__(256) void cproj_mfma(
    const float* __restrict__ c, const float* __restrict__ W,
    const float* __restrict__ bias, const int* __restrict__ kptr,
    float* __restrict__ cp) {
    const int ksel = kptr[0];
    const float* __restrict__ Wk = W + (size_t)ksel * DIM * DIM;
    const float* __restrict__ bk = bias + (size_t)ksel * DIM;

    __shared__ short Alds[64][K1_PAD];
    __shared__ short Blds[64][K1_PAD];

    const int bm = blockIdx.x & 31;
    const int bn = blockIdx.x >> 5;
    const int t  = threadIdx.x;
    const int lane = t & 63;
    const int wv   = t >> 6;

    const int srow = t >> 2;
    const int sk   = (t & 3) * 8;

    const float* Ap = c  + (size_t)(bm * 64 + srow) * DIM + sk;
    const float* Bp = Wk + (size_t)(bn * 64 + srow) * DIM + sk;

    float4 a0 = *(const float4*)Ap,       a1 = *(const float4*)(Ap + 4);
    float4 b0 = *(const float4*)Bp,       b1 = *(const float4*)(Bp + 4);

    f32x4 acc[4] = {};

    const int frow = lane & 15;
    const int fk   = (lane >> 4) * 8;

    for (int step = 0; step < 16; ++step) {
        __syncthreads();
        short8 av, bv;
        av[0] = f2bf(a0.x); av[1] = f2bf(a0.y); av[2] = f2bf(a0.z); av[3] = f2bf(a0.w);
        av[4] = f2bf(a1.x); av[5] = f2bf(a1.y); av[6] = f2bf(a1.z); av[7] = f2bf(a1.w);
        bv[0] = f2bf(b0.x); bv[1] = f2bf(b0.y); bv[2] = f2bf(b0.z); bv[3] = f2bf(b0.w);
        bv[4] = f2bf(b1.x); bv[5] = f2bf(b1.y); bv[6] = f2bf(b1.z); bv[7] = f2bf(b1.w);
        *(short8*)&Alds[srow][sk] = av;
        *(short8*)&Blds[srow][sk] = bv;
        __syncthreads();
        if (step < 15) {
            const int off = (step + 1) * 32;
            a0 = *(const float4*)(Ap + off); a1 = *(const float4*)(Ap + off + 4);
            b0 = *(const float4*)(Bp + off); b1 = *(const float4*)(Bp + off + 4);
        }
        const short8 bfrag = *(const short8*)&Blds[wv * 16 + frow][fk];
#pragma unroll
        for (int f = 0; f < 4; ++f) {
            const short8 afrag = *(const short8*)&Alds[f * 16 + frow][fk];
            acc[f] = __builtin_amdgcn_mfma_f32_16x16x32_bf16(afrag, bfrag, acc[f], 0, 0, 0);
        }
    }

    const int col = bn * 64 + wv * 16 + frow;
    const float bias_v = bk[col];
    const int r0 = (lane >> 4) * 4;
#pragma unroll
    for (int f = 0; f < 4; ++f)
#pragma unroll
        for (int r = 0; r < 4; ++r)
            cp[(size_t)(bm * 64 + f * 16 + r0 + r) * DIM + col] = acc[f][r] + bias_v;
}

// ---------------- Kernel 2: out[b,n,s] = (1/512) * dot(cp[b,s,:], z[b,n,s,:]) ----
// MAX-INJECTION variant: 16384 short blocks (8 per (b,s) row). Each wave owns
// 4 n's, ALL loaded in the prologue (2 cp + 8 z loads in flight at wave
// birth), then 4 dot+reduce+store steps and exit. Short blocks keep the
// dispatcher injecting fresh waves whose loads issue immediately — maximizing
// outstanding read requests per CU without per-wave register depth.
#define NS ((size_t)128 * 512)         // n-stride in z (floats)
#define LD4(p) (*(const float4*)(p))

__global__ __launch_bounds__(256) void dot_kernel(
    const float* __restrict__ z, const float* __restrict__ cp,
    float* __restrict__ out) {
    const int blk  = blockIdx.x;             // 0..16383
    const int bs   = blk >> 3;               // b*128 + s (0..2047)
    const int noct = blk & 7;                // n-group of 16
    const int wave = threadIdx.x >> 6;       // 0..3
    const int lane = threadIdx.x & 63;
    const int b = bs >> 7;
    const int s = bs & 127;

    // cp row -> registers, contiguous 1 KB halves (L1-broadcast across waves)
    const float* cpr = cp + (size_t)bs * DIM + lane * 4;
    const float4 c0 = LD4(cpr);
    const float4 c1 = LD4(cpr + 256);

    // wave's 4 n's: n = noct*16 + wave*4 + i, i = 0..3
    const int nbase = noct * 16 + wave * 4;
    const float* zp = z + (((size_t)(b * 128 + nbase)) * 128 + s) * DIM + lane * 4;
    float* outp = out + ((size_t)(b * 128 + nbase)) * 128 + s;

    // prologue: all 4 slots issued (8 z loads + 2 cp loads in flight)
    const float4 zA0 = LD4(zp + 0 * NS), zA1 = LD4(zp + 0 * NS + 256);
    const float4 zB0 = LD4(zp + 1 * NS), zB1 = LD4(zp + 1 * NS + 256);
    const float4 zC0 = LD4(zp + 2 * NS), zC1 = LD4(zp + 2 * NS + 256);
    const float4 zD0 = LD4(zp + 3 * NS), zD1 = LD4(zp + 3 * NS + 256);

#define SLOT(Z0, Z1, II)                                                      \
    {                                                                          \
        float acc = Z0.x * c0.x;                                               \
        acc = fmaf(Z0.y, c0.y, acc);                                           \
        acc = fmaf(Z0.z, c0.z, acc);                                           \
        acc = fmaf(Z0.w, c0.w, acc);                                           \
        acc = fmaf(Z1.x, c1.x, acc);                                           \
        acc = fmaf(Z1.y, c1.y, acc);                                           \
        acc = fmaf(Z1.z, c1.z, acc);                                           \
        acc = fmaf(Z1.w, c1.w, acc);                                           \
        _Pragma("unroll")                                                      \
        for (int off = 32; off; off >>= 1) acc += __shfl_xor(acc, off);        \
        if (lane == 0) outp[(size_t)(II) * 128] = acc * (1.0f / 512.0f);       \
    }

    SLOT(zA0, zA1, 0)
    SLOT(zB0, zB1, 1)
    SLOT(zC0, zC1, 2)
    SLOT(zD0, zD1, 3)
#undef SLOT
}

extern "C" void kernel_launch(void* const* d_in, const int* in_sizes, int n_in,
                              void* d_out, int out_size, void* d_ws, size_t ws_size,
                              hipStream_t stream) {
    const float* c    = (const float*)d_in[0];
    const float* z    = (const float*)d_in[1];
    const float* W    = (const float*)d_in[2];
    const float* bias = (const float*)d_in[3];
    const int*   kptr = (const int*)d_in[4];
    float* out = (float*)d_out;
    float* cp  = (float*)d_ws;   // 2048*512*4 = 4 MB scratch for c_proj

    // Kernel 1: 32 M-tiles x 8 N-tiles = 256 blocks, bf16 MFMA
    cproj_mfma<<<dim3(256), dim3(256), 0, stream>>>(c, W, bias, kptr, cp);
    // Kernel 2: 16384 short blocks (8 per (b,s) row), one-shot 4-slot waves
    dot_kernel<<<dim3(16384), dim3(256), 0, stream>>>(z, cp, out);
}